// Round 11
// baseline (335.982 us; speedup 1.0000x reference)
//
#include <hip/hip_runtime.h>
#include <hip/hip_fp16.h>

#define D 64

// ---------------- degree + rank ----------------
// rank[e] = this edge's arrival index at its target -> later a unique CSR slot.

__global__ void deg_rank_k(const int* __restrict__ col, unsigned int* deg,
                           unsigned int* __restrict__ rank, int E) {
    int e = blockIdx.x * blockDim.x + threadIdx.x;
    if (e < E) rank[e] = atomicAdd(&deg[col[e]], 1u);
}

// ---------------- dinv + scan-free CSR segment allocation + fused f2h ----------------
// seg[i] = {start, cnt} for hops; start_p[i] = start (4B table for bucket gather).
// Tail of the kernel converts this block's 256-node x-slab to fp16, coalesced.

__global__ __launch_bounds__(256) void alloc_f2h_k(const unsigned int* __restrict__ deg,
                                                   float* __restrict__ dinv,
                                                   uint2* __restrict__ seg,
                                                   unsigned int* __restrict__ start_p,
                                                   unsigned int* cursor,
                                                   const float* __restrict__ x,
                                                   __half* __restrict__ xh, int n) {
    int i = blockIdx.x * blockDim.x + threadIdx.x;
    int lane = threadIdx.x & 63;
    unsigned int cnt = (i < n) ? deg[i] : 0u;          // in-edges
    if (i < n) dinv[i] = rsqrtf((float)(cnt + 1u));    // +1 self-loop
    unsigned int v = cnt;  // inclusive wave scan
#pragma unroll
    for (int off = 1; off < 64; off <<= 1) {
        unsigned int t = (unsigned int)__shfl_up((int)v, off, 64);
        if (lane >= off) v += t;
    }
    unsigned int base = 0;
    if (lane == 63) base = atomicAdd(cursor, v);
    base = (unsigned int)__shfl((int)base, 63, 64);
    if (i < n) {
        unsigned int start = base + v - cnt;
        seg[i] = make_uint2(start, cnt);
        start_p[i] = start;
    }
    // coalesced fp32->fp16 of this block's 256-node slab (256 nodes * 16 float4)
    size_t base4 = (size_t)blockIdx.x * 4096;
    size_t limit4 = (size_t)n * 16;
    for (int t = threadIdx.x; t < 4096; t += 256) {
        size_t idx = base4 + t;
        if (idx < limit4) {
            float4 vv = ((const float4*)x)[idx];
            union { __half2 h[2]; float2 f; } u;
            u.h[0] = __float22half2_rn(make_float2(vv.x, vv.y));
            u.h[1] = __float22half2_rn(make_float2(vv.z, vv.w));
            ((float2*)xh)[idx] = u.f;
        }
    }
}

// ---------------- bucket edges into CSR: NO atomics ----------------
// pos = start[i] + rank[e] is unique; chain is gather(hot 4B) -> store(8B).

__global__ void bucket_k(const int* __restrict__ row, const int* __restrict__ col,
                         const unsigned int* __restrict__ rank,
                         const unsigned int* __restrict__ start_p,
                         const float* __restrict__ dinv,
                         int2* __restrict__ csr, int E) {
    int e = blockIdx.x * blockDim.x + threadIdx.x;
    if (e >= E) return;
    int j = row[e], i = col[e];
    unsigned int pos = start_p[i] + rank[e];
    csr[pos] = make_int2(j, __float_as_int(dinv[j] * dinv[i]));
}

// ---------------- helpers ----------------

__device__ __forceinline__ void fma_row8(float acc[8], float wgt, float4 raw) {
    const __half2* q = (const __half2*)&raw;
#pragma unroll
    for (int k = 0; k < 4; ++k) {
        float2 f = __half22float2(q[k]);
        acc[2 * k]     = fmaf(wgt, f.x, acc[2 * k]);
        acc[2 * k + 1] = fmaf(wgt, f.y, acc[2 * k + 1]);
    }
}

// Per-slot edge aggregation, unroll 8: 8-lane group owns node i; up to 8
// independent row-gather chains in flight per iteration (avg degree 16 -> ~2 iters).
__device__ __forceinline__ void aggregate_node(const __half* __restrict__ h_in,
                                               const int2* __restrict__ csr,
                                               uint2 sg, int fb, float acc[8]) {
    float a1[8];
#pragma unroll
    for (int k = 0; k < 8; ++k) { acc[k] = 0.0f; a1[k] = 0.0f; }
    unsigned int e = sg.x, end = sg.x + sg.y;
    for (; e + 8 <= end; e += 8) {
        int2 p[8];
#pragma unroll
        for (int k = 0; k < 8; ++k) p[k] = csr[e + k];
        float4 r[8];
#pragma unroll
        for (int k = 0; k < 8; ++k) r[k] = *(const float4*)(h_in + (size_t)p[k].x * D + fb);
#pragma unroll
        for (int k = 0; k < 8; ++k) fma_row8((k & 1) ? a1 : acc, __int_as_float(p[k].y), r[k]);
    }
    if (e + 4 <= end) {
        int2 p0 = csr[e], p1 = csr[e + 1], p2 = csr[e + 2], p3 = csr[e + 3];
        float4 r0 = *(const float4*)(h_in + (size_t)p0.x * D + fb);
        float4 r1 = *(const float4*)(h_in + (size_t)p1.x * D + fb);
        float4 r2 = *(const float4*)(h_in + (size_t)p2.x * D + fb);
        float4 r3 = *(const float4*)(h_in + (size_t)p3.x * D + fb);
        fma_row8(acc, __int_as_float(p0.y), r0);
        fma_row8(a1,  __int_as_float(p1.y), r1);
        fma_row8(acc, __int_as_float(p2.y), r2);
        fma_row8(a1,  __int_as_float(p3.y), r3);
        e += 4;
    }
    for (; e < end; ++e) {
        int2 p = csr[e];
        float4 r = *(const float4*)(h_in + (size_t)p.x * D + fb);
        fma_row8(acc, __int_as_float(p.y), r);
    }
#pragma unroll
    for (int k = 0; k < 8; ++k) acc[k] += a1[k];
}

// ---------------- hop 1: wave = 8 nodes, 8 lanes per node ----------------

__global__ __launch_bounds__(256) void hop8s_k(const __half* __restrict__ h_in,
                                               const float* __restrict__ dinv,
                                               const uint2* __restrict__ seg,
                                               const int2* __restrict__ csr,
                                               __half* __restrict__ h_out, int n) {
    int wave = blockIdx.x * 4 + (threadIdx.x >> 6);
    int lane = threadIdx.x & 63;
    int g = lane >> 3;          // node slot 0..7
    int fb = (lane & 7) << 3;   // feature base (8 halves = 16B)
    int i = wave * 8 + g;
    bool valid = (i < n);
    uint2 sg = valid ? seg[i] : make_uint2(0u, 0u);
    float acc[8];
    aggregate_node(h_in, csr, sg, fb, acc);
    if (valid) {
        float di = dinv[i];
        float4 s = *(const float4*)(h_in + (size_t)i * D + fb);
        fma_row8(acc, di * di, s);  // self-loop term
        float4 outv;
        __half2* o = (__half2*)&outv;
        o[0] = __float22half2_rn(make_float2(acc[0], acc[1]));
        o[1] = __float22half2_rn(make_float2(acc[2], acc[3]));
        o[2] = __float22half2_rn(make_float2(acc[4], acc[5]));
        o[3] = __float22half2_rn(make_float2(acc[6], acc[7]));
        *(float4*)(h_out + (size_t)i * D + fb) = outv;
    }
}

// ---------------- hop 2 fused with Linear + bias + ReLU (fp32 math) ----------------

__global__ __launch_bounds__(256) void hop8s_linear_k(const __half* __restrict__ h_in,
                                                      const float* __restrict__ dinv,
                                                      const uint2* __restrict__ seg,
                                                      const int2* __restrict__ csr,
                                                      const float* __restrict__ W,
                                                      const float* __restrict__ b,
                                                      float* __restrict__ out, int n) {
    __shared__ float Wt[D][D + 1];   // Wt[d][o] = W[o][d]; +1 pad -> conflict-free
    __shared__ float sh[4][8][D];    // per-wave: 8 aggregated node rows (fp32)
    int tid = threadIdx.x;
    for (int k = tid; k < D * D; k += 256) Wt[k & 63][k >> 6] = W[k];
    __syncthreads();
    int w = tid >> 6, lane = tid & 63;
    int wave = blockIdx.x * 4 + w;
    int g = lane >> 3;
    int fb = (lane & 7) << 3;
    int i = wave * 8 + g;
    bool valid = (i < n);
    uint2 sg = valid ? seg[i] : make_uint2(0u, 0u);
    float acc[8];
    aggregate_node(h_in, csr, sg, fb, acc);
    if (valid) {
        float di = dinv[i];
        float4 s = *(const float4*)(h_in + (size_t)i * D + fb);
        fma_row8(acc, di * di, s);
        *(float4*)&sh[w][g][fb]     = make_float4(acc[0], acc[1], acc[2], acc[3]);
        *(float4*)&sh[w][g][fb + 4] = make_float4(acc[4], acc[5], acc[6], acc[7]);
    }
    // readers are the SAME wave -> compiler inserts lgkmcnt wait; no barrier needed
    float bias = b[lane];
#pragma unroll 1
    for (int nd = 0; nd < 8; ++nd) {
        int i2 = wave * 8 + nd;       // wave-uniform
        if (i2 >= n) break;
        float o = bias;
#pragma unroll
        for (int d = 0; d < D; ++d) o = fmaf(sh[w][nd][d], Wt[d][lane], o);
        out[(size_t)i2 * D + lane] = fmaxf(o, 0.0f);
    }
}

// ---------------- launch ----------------

extern "C" void kernel_launch(void* const* d_in, const int* in_sizes, int n_in,
                              void* d_out, int out_size, void* d_ws, size_t ws_size,
                              hipStream_t stream) {
    const float* x = (const float*)d_in[0];  // [n, 64]
    const float* W = (const float*)d_in[1];  // [64, 64]
    const float* b = (const float*)d_in[2];  // [64]
    const int*   ei = (const int*)d_in[3];   // [2, E] int32

    const int n = in_sizes[0] / D;
    const int E = in_sizes[3] / 2;
    const int* row = ei;       // sources j
    const int* col = ei + E;   // targets i
    float* out = (float*)d_out;

    // ws (~47 MB): deg | cursor | dinv | start_p | seg | rank | csr(int2) | xh | h1h
    // deg and cursor adjacent -> one memset zeroes both.
    char* ws = (char*)d_ws;
    size_t off = 0;
    unsigned int* deg     = (unsigned int*)(ws + off); off += (size_t)n * 4;
    unsigned int* cursor  = (unsigned int*)(ws + off); off += 16;
    float*        dinv    = (float*)(ws + off);        off += (size_t)n * 4;
    unsigned int* start_p = (unsigned int*)(ws + off); off += (size_t)n * 4;
    uint2*        seg     = (uint2*)(ws + off);        off += (size_t)n * 8;
    unsigned int* rank    = (unsigned int*)(ws + off); off += (size_t)E * 4;
    int2*         csr     = (int2*)(ws + off);         off += (size_t)E * 8;
    __half*       xh      = (__half*)(ws + off);       off += (size_t)n * D * 2;
    __half*       h1h     = (__half*)(ws + off);       off += (size_t)n * D * 2;

    const int nb = (n + 255) / 256;
    const int eb = (E + 255) / 256;
    const int gb = (n + 31) / 32;     // wave = 8 nodes, block = 32 nodes

    hipMemsetAsync(deg, 0, (size_t)n * 4 + 16, stream);  // deg + cursor
    deg_rank_k<<<eb, 256, 0, stream>>>(col, deg, rank, E);
    alloc_f2h_k<<<nb, 256, 0, stream>>>(deg, dinv, seg, start_p, cursor, x, xh, n);
    bucket_k<<<eb, 256, 0, stream>>>(row, col, rank, start_p, dinv, csr, E);

    hop8s_k<<<gb, 256, 0, stream>>>(xh, dinv, seg, csr, h1h, n);
    hop8s_linear_k<<<gb, 256, 0, stream>>>(h1h, dinv, seg, csr, W, b, out, n);
}

// Round 12
// 330.214 us; speedup vs baseline: 1.0175x; 1.0175x over previous
//
#include <hip/hip_runtime.h>
#include <hip/hip_fp16.h>

#define D 64

// ---------------- degree + rank ----------------
// rank[e] = this edge's arrival index at its target -> later a unique CSR slot.

__global__ void deg_rank_k(const int* __restrict__ col, unsigned int* deg,
                           unsigned int* __restrict__ rank, int E) {
    int e = blockIdx.x * blockDim.x + threadIdx.x;
    if (e < E) rank[e] = atomicAdd(&deg[col[e]], 1u);
}

// ---------------- dinv + scan-free CSR segment allocation ----------------
// seg[i] = {start, cnt} for hops; start_p[i] = start (4B table for bucket gather).

__global__ void alloc_k(const unsigned int* __restrict__ deg, float* __restrict__ dinv,
                        uint2* __restrict__ seg, unsigned int* __restrict__ start_p,
                        unsigned int* cursor, int n) {
    int i = blockIdx.x * blockDim.x + threadIdx.x;
    int lane = threadIdx.x & 63;
    unsigned int cnt = (i < n) ? deg[i] : 0u;          // in-edges
    if (i < n) dinv[i] = rsqrtf((float)(cnt + 1u));    // +1 self-loop
    unsigned int v = cnt;  // inclusive wave scan
#pragma unroll
    for (int off = 1; off < 64; off <<= 1) {
        unsigned int t = (unsigned int)__shfl_up((int)v, off, 64);
        if (lane >= off) v += t;
    }
    unsigned int base = 0;
    if (lane == 63) base = atomicAdd(cursor, v);
    base = (unsigned int)__shfl((int)base, 63, 64);
    if (i < n) {
        unsigned int start = base + v - cnt;
        seg[i] = make_uint2(start, cnt);
        start_p[i] = start;
    }
}

// ---------------- bucket edges into CSR: NO atomics ----------------
// pos = start[i] + rank[e] is unique; chain is gather(hot 4B) -> store(8B).

__global__ void bucket_k(const int* __restrict__ row, const int* __restrict__ col,
                         const unsigned int* __restrict__ rank,
                         const unsigned int* __restrict__ start_p,
                         const float* __restrict__ dinv,
                         int2* __restrict__ csr, int E) {
    int e = blockIdx.x * blockDim.x + threadIdx.x;
    if (e >= E) return;
    int j = row[e], i = col[e];
    unsigned int pos = start_p[i] + rank[e];
    csr[pos] = make_int2(j, __float_as_int(dinv[j] * dinv[i]));
}

// ---------------- fp32 -> fp16 feature conversion (standalone streaming pass) ----------

__global__ void f2h_k(const float* __restrict__ x, __half* __restrict__ xh, int n16) {
    int t = blockIdx.x * blockDim.x + threadIdx.x;  // n*16 threads, 4 floats each
    if (t >= n16) return;
    float4 v = ((const float4*)x)[t];
    union { __half2 h[2]; float2 f; } u;
    u.h[0] = __float22half2_rn(make_float2(v.x, v.y));
    u.h[1] = __float22half2_rn(make_float2(v.z, v.w));
    ((float2*)xh)[t] = u.f;
}

// ---------------- helpers ----------------

__device__ __forceinline__ void fma_row8(float acc[8], float wgt, float4 raw) {
    const __half2* q = (const __half2*)&raw;
#pragma unroll
    for (int k = 0; k < 4; ++k) {
        float2 f = __half22float2(q[k]);
        acc[2 * k]     = fmaf(wgt, f.x, acc[2 * k]);
        acc[2 * k + 1] = fmaf(wgt, f.y, acc[2 * k + 1]);
    }
}

// Per-slot edge aggregation, unroll 8: 8-lane group owns node i; up to 8
// independent row-gather chains in flight per iteration (avg degree 16 -> ~2 iters).
__device__ __forceinline__ void aggregate_node(const __half* __restrict__ h_in,
                                               const int2* __restrict__ csr,
                                               uint2 sg, int fb, float acc[8]) {
    float a1[8];
#pragma unroll
    for (int k = 0; k < 8; ++k) { acc[k] = 0.0f; a1[k] = 0.0f; }
    unsigned int e = sg.x, end = sg.x + sg.y;
    for (; e + 8 <= end; e += 8) {
        int2 p[8];
#pragma unroll
        for (int k = 0; k < 8; ++k) p[k] = csr[e + k];
        float4 r[8];
#pragma unroll
        for (int k = 0; k < 8; ++k) r[k] = *(const float4*)(h_in + (size_t)p[k].x * D + fb);
#pragma unroll
        for (int k = 0; k < 8; ++k) fma_row8((k & 1) ? a1 : acc, __int_as_float(p[k].y), r[k]);
    }
    if (e + 4 <= end) {
        int2 p0 = csr[e], p1 = csr[e + 1], p2 = csr[e + 2], p3 = csr[e + 3];
        float4 r0 = *(const float4*)(h_in + (size_t)p0.x * D + fb);
        float4 r1 = *(const float4*)(h_in + (size_t)p1.x * D + fb);
        float4 r2 = *(const float4*)(h_in + (size_t)p2.x * D + fb);
        float4 r3 = *(const float4*)(h_in + (size_t)p3.x * D + fb);
        fma_row8(acc, __int_as_float(p0.y), r0);
        fma_row8(a1,  __int_as_float(p1.y), r1);
        fma_row8(acc, __int_as_float(p2.y), r2);
        fma_row8(a1,  __int_as_float(p3.y), r3);
        e += 4;
    }
    for (; e < end; ++e) {
        int2 p = csr[e];
        float4 r = *(const float4*)(h_in + (size_t)p.x * D + fb);
        fma_row8(acc, __int_as_float(p.y), r);
    }
#pragma unroll
    for (int k = 0; k < 8; ++k) acc[k] += a1[k];
}

// ---------------- hop 1: wave = 8 nodes, 8 lanes per node ----------------

__global__ __launch_bounds__(256) void hop8s_k(const __half* __restrict__ h_in,
                                               const float* __restrict__ dinv,
                                               const uint2* __restrict__ seg,
                                               const int2* __restrict__ csr,
                                               __half* __restrict__ h_out, int n) {
    int wave = blockIdx.x * 4 + (threadIdx.x >> 6);
    int lane = threadIdx.x & 63;
    int g = lane >> 3;          // node slot 0..7
    int fb = (lane & 7) << 3;   // feature base (8 halves = 16B)
    int i = wave * 8 + g;
    bool valid = (i < n);
    uint2 sg = valid ? seg[i] : make_uint2(0u, 0u);
    float acc[8];
    aggregate_node(h_in, csr, sg, fb, acc);
    if (valid) {
        float di = dinv[i];
        float4 s = *(const float4*)(h_in + (size_t)i * D + fb);
        fma_row8(acc, di * di, s);  // self-loop term
        float4 outv;
        __half2* o = (__half2*)&outv;
        o[0] = __float22half2_rn(make_float2(acc[0], acc[1]));
        o[1] = __float22half2_rn(make_float2(acc[2], acc[3]));
        o[2] = __float22half2_rn(make_float2(acc[4], acc[5]));
        o[3] = __float22half2_rn(make_float2(acc[6], acc[7]));
        *(float4*)(h_out + (size_t)i * D + fb) = outv;
    }
}

// ---------------- hop 2 fused with Linear + bias + ReLU (fp32 math) ----------------

__global__ __launch_bounds__(256) void hop8s_linear_k(const __half* __restrict__ h_in,
                                                      const float* __restrict__ dinv,
                                                      const uint2* __restrict__ seg,
                                                      const int2* __restrict__ csr,
                                                      const float* __restrict__ W,
                                                      const float* __restrict__ b,
                                                      float* __restrict__ out, int n) {
    __shared__ float Wt[D][D + 1];   // Wt[d][o] = W[o][d]; +1 pad -> conflict-free
    __shared__ float sh[4][8][D];    // per-wave: 8 aggregated node rows (fp32)
    int tid = threadIdx.x;
    for (int k = tid; k < D * D; k += 256) Wt[k & 63][k >> 6] = W[k];
    __syncthreads();
    int w = tid >> 6, lane = tid & 63;
    int wave = blockIdx.x * 4 + w;
    int g = lane >> 3;
    int fb = (lane & 7) << 3;
    int i = wave * 8 + g;
    bool valid = (i < n);
    uint2 sg = valid ? seg[i] : make_uint2(0u, 0u);
    float acc[8];
    aggregate_node(h_in, csr, sg, fb, acc);
    if (valid) {
        float di = dinv[i];
        float4 s = *(const float4*)(h_in + (size_t)i * D + fb);
        fma_row8(acc, di * di, s);
        *(float4*)&sh[w][g][fb]     = make_float4(acc[0], acc[1], acc[2], acc[3]);
        *(float4*)&sh[w][g][fb + 4] = make_float4(acc[4], acc[5], acc[6], acc[7]);
    }
    // readers are the SAME wave -> compiler inserts lgkmcnt wait; no barrier needed
    float bias = b[lane];
#pragma unroll 1
    for (int nd = 0; nd < 8; ++nd) {
        int i2 = wave * 8 + nd;       // wave-uniform
        if (i2 >= n) break;
        float o = bias;
#pragma unroll
        for (int d = 0; d < D; ++d) o = fmaf(sh[w][nd][d], Wt[d][lane], o);
        out[(size_t)i2 * D + lane] = fmaxf(o, 0.0f);
    }
}

// ---------------- launch ----------------

extern "C" void kernel_launch(void* const* d_in, const int* in_sizes, int n_in,
                              void* d_out, int out_size, void* d_ws, size_t ws_size,
                              hipStream_t stream) {
    const float* x = (const float*)d_in[0];  // [n, 64]
    const float* W = (const float*)d_in[1];  // [64, 64]
    const float* b = (const float*)d_in[2];  // [64]
    const int*   ei = (const int*)d_in[3];   // [2, E] int32

    const int n = in_sizes[0] / D;
    const int E = in_sizes[3] / 2;
    const int* row = ei;       // sources j
    const int* col = ei + E;   // targets i
    float* out = (float*)d_out;

    // ws (~47 MB): deg | cursor | dinv | start_p | seg | rank | csr(int2) | xh | h1h
    // deg and cursor adjacent -> one memset zeroes both.
    char* ws = (char*)d_ws;
    size_t off = 0;
    unsigned int* deg     = (unsigned int*)(ws + off); off += (size_t)n * 4;
    unsigned int* cursor  = (unsigned int*)(ws + off); off += 16;
    float*        dinv    = (float*)(ws + off);        off += (size_t)n * 4;
    unsigned int* start_p = (unsigned int*)(ws + off); off += (size_t)n * 4;
    uint2*        seg     = (uint2*)(ws + off);        off += (size_t)n * 8;
    unsigned int* rank    = (unsigned int*)(ws + off); off += (size_t)E * 4;
    int2*         csr     = (int2*)(ws + off);         off += (size_t)E * 8;
    __half*       xh      = (__half*)(ws + off);       off += (size_t)n * D * 2;
    __half*       h1h     = (__half*)(ws + off);       off += (size_t)n * D * 2;

    const int nb = (n + 255) / 256;
    const int eb = (E + 255) / 256;
    const int gb = (n + 31) / 32;     // wave = 8 nodes, block = 32 nodes
    const int cb = (n * 16 + 255) / 256;

    hipMemsetAsync(deg, 0, (size_t)n * 4 + 16, stream);  // deg + cursor
    deg_rank_k<<<eb, 256, 0, stream>>>(col, deg, rank, E);
    alloc_k<<<nb, 256, 0, stream>>>(deg, dinv, seg, start_p, cursor, n);
    bucket_k<<<eb, 256, 0, stream>>>(row, col, rank, start_p, dinv, csr, E);
    f2h_k<<<cb, 256, 0, stream>>>(x, xh, n * 16);

    hop8s_k<<<gb, 256, 0, stream>>>(xh, dinv, seg, csr, h1h, n);
    hop8s_linear_k<<<gb, 256, 0, stream>>>(h1h, dinv, seg, csr, W, b, out, n);
}